// Round 2
// baseline (619.045 us; speedup 1.0000x reference)
//
#include <hip/hip_runtime.h>
#include <hip/hip_bf16.h>

// Problem constants (fixed by setup_inputs)
#define NNODES 16384      // B*n = 8*2048
#define KEDGE  16
#define CIN    64
#define HID    64
#define OUTC   128
#define EPS    1e-5f

// Workspace layout (floats):
//   y1  : NNODES*64  = 1,048,576   (pre-BN1 node features)
//   t2  : NNODES*128 = 2,097,152   (pre-BN2)
//   st1 : 128  (sum[64], sumsq[64])
//   st2 : 256  (sum[0..127], sumsq[128..255])
#define Y1_OFF  0
#define T2_OFF  1048576
#define ST1_OFF 3145728
#define ST2_OFF (ST1_OFF + 128)

// ---------------------------------------------------------------------------
// Kernel 1: fused edge aggregation + 390x64 GEMM + BN1 stats.
// One wave per node. Lane = channel for the vector parts.
//
// Edge-scalar work (cos^2, weights, signs) is lane-invariant per edge, so it
// is computed once by lane group j = lane&15 (4 redundant copies — free, same
// wave-instr count) and broadcast, instead of 64x redundantly as in round 1.
// The six 64-vectors A_s + six scalars beta_s then contract against
// [lins_W; lins_b] directly from LDS — the (16384 x 390) A matrix never
// touches global memory.
// ---------------------------------------------------------------------------
__global__ __launch_bounds__(256) void k_node(
    const float* __restrict__ x, const float* __restrict__ p,
    const int* __restrict__ sid, const int* __restrict__ tid,
    const float* __restrict__ W, const float* __restrict__ bias,
    float* __restrict__ y1, float* __restrict__ st1)
{
    __shared__ float Ash[4][392];   // 384 used per wave; 392 keeps rows 16B-aligned

    const int lane = threadIdx.x & 63;
    const int wv   = threadIdx.x >> 6;
    const int t    = blockIdx.x * 4 + wv;
    const int base = t * KEDGE;

    // ---- phase 1: per-edge scalars (edge j handled by lanes j, j+16, j+32, j+48)
    const int j  = lane & 15;
    const int s  = sid[base + j];
    const int tn = tid[base];
    const float ptx = p[tn*3+0], pty = p[tn*3+1], ptz = p[tn*3+2];

    const float dx = p[s*3+0] - ptx;
    const float dy = p[s*3+1] - pty;
    const float dz = p[s*3+2] - ptz;
    float pd = sqrtf(dx*dx + dy*dy + dz*dz);
    pd = fmaxf(pd, 1e-16f);

    // max(pd) over the node's 16 edges (butterfly stays inside each 16-group)
    float pr = pd;
    pr = fmaxf(pr, __shfl_xor(pr, 1));
    pr = fmaxf(pr, __shfl_xor(pr, 2));
    pr = fmaxf(pr, __shfl_xor(pr, 4));
    pr = fmaxf(pr, __shfl_xor(pr, 8));
    pr *= 1.1f;

    float w = pr - pd; w = w * w;
    float wsum = w;
    wsum += __shfl_xor(wsum, 1);
    wsum += __shfl_xor(wsum, 2);
    wsum += __shfl_xor(wsum, 4);
    wsum += __shfl_xor(wsum, 8);
    w = w / wsum;

    const float invd = 1.f / pd;
    float c0 = cosf(dx * invd);
    float c1 = cosf(dy * invd);
    float c2 = cosf(dz * invd);
    const float w0 = w * c0 * c0;
    const float w1 = w * c1 * c1;
    const float w2 = w * c2 * c2;
    const int flags = (dx > 0.f ? 1 : 0) | (dy > 0.f ? 2 : 0) | (dz > 0.f ? 4 : 0);

    // ---- phase 2: gather x rows and accumulate the six A vectors + betas
    const float xt = x[tn*64 + lane];
    float ev[KEDGE];
    #pragma unroll
    for (int jj = 0; jj < KEDGE; ++jj) {
        int sv = __shfl(s, jj);
        ev[jj] = x[sv*64 + lane];
    }

    float A0=0,A1=0,A2=0,A3=0,A4=0,A5=0;
    float B0=0,B1=0,B2=0,B3=0,B4=0,B5=0;
    #pragma unroll
    for (int jj = 0; jj < KEDGE; ++jj) {
        const float wq0 = __shfl(w0, jj);
        const float wq1 = __shfl(w1, jj);
        const float wq2 = __shfl(w2, jj);
        const int   f   = __builtin_amdgcn_readfirstlane(__shfl(flags, jj));
        const float e   = ev[jj] - xt;
        if (f & 1) { A1 += wq0*e; B1 += wq0; } else { A0 += wq0*e; B0 += wq0; }
        if (f & 2) { A3 += wq1*e; B3 += wq1; } else { A2 += wq1*e; B2 += wq1; }
        if (f & 4) { A5 += wq2*e; B5 += wq2; } else { A4 += wq2*e; B4 += wq2; }
    }

    // ---- phase 3: y = [A0..A5] @ lins_W + [B0..B5] @ lins_b
    Ash[wv][0*64+lane] = A0; Ash[wv][1*64+lane] = A1; Ash[wv][2*64+lane] = A2;
    Ash[wv][3*64+lane] = A3; Ash[wv][4*64+lane] = A4; Ash[wv][5*64+lane] = A5;
    // wave-private LDS region: compiler inserts lgkmcnt wait, no barrier needed

    const float* Wp = W + lane;
    float a0=0.f, a1=0.f, a2=0.f, a3=0.f;
    #pragma unroll 4
    for (int k = 0; k < 384; k += 4) {
        const float4 av = *(const float4*)&Ash[wv][k];   // uniform addr -> broadcast
        a0 += av.x * Wp[(k+0)*64];
        a1 += av.y * Wp[(k+1)*64];
        a2 += av.z * Wp[(k+2)*64];
        a3 += av.w * Wp[(k+3)*64];
    }
    float acc = (a0 + a1) + (a2 + a3);
    acc += B0*bias[0*64+lane] + B1*bias[1*64+lane] + B2*bias[2*64+lane]
         + B3*bias[3*64+lane] + B4*bias[4*64+lane] + B5*bias[5*64+lane];

    y1[t*64 + lane] = acc;
    atomicAdd(&st1[lane],      acc);
    atomicAdd(&st1[64 + lane], acc*acc);
}

// ---------------------------------------------------------------------------
// Kernel 2: t2 = x@lin1_W + relu(bn1(y1))@lin2_W + (lin1_b+lin2_b),
// with BN2 stats fused (per-wave partial over 4 rows -> 1 atomic/lane).
// One wave handles 4 rows; lane covers output cols {lane, lane+64}.
// ---------------------------------------------------------------------------
__global__ __launch_bounds__(256) void k_fused2(
    const float* __restrict__ x, const int* __restrict__ tid,
    const float* __restrict__ y1, const float* __restrict__ stats1,
    const float* __restrict__ g1, const float* __restrict__ b1,
    const float* __restrict__ W1, const float* __restrict__ bias1,
    const float* __restrict__ W2, const float* __restrict__ bias2,
    float* __restrict__ t2, float* __restrict__ st2)
{
    const int lane = threadIdx.x & 63;
    const int wv   = threadIdx.x >> 6;
    const int r0   = (blockIdx.x * 4 + wv) * 4;

    const float mu  = stats1[lane] * (1.f / NNODES);
    const float var = stats1[64 + lane] * (1.f / NNODES) - mu*mu;
    const float sc  = rsqrtf(var + EPS) * g1[lane];
    const float sh  = b1[lane] - mu*sc;

    float xv[4], zv[4];
    #pragma unroll
    for (int i = 0; i < 4; ++i) {
        const int tn = tid[(r0 + i) * KEDGE];
        xv[i] = x[tn*64 + lane];
        const float yv = y1[(r0 + i)*64 + lane];
        zv[i] = fmaxf(yv*sc + sh, 0.f);
    }
    float a0[4] = {0,0,0,0}, a1[4] = {0,0,0,0};
    #pragma unroll 4
    for (int k = 0; k < 64; ++k) {
        const float w1a = W1[k*128 + lane],      w1b = W1[k*128 + 64 + lane];
        const float w2a = W2[k*128 + lane],      w2b = W2[k*128 + 64 + lane];
        #pragma unroll
        for (int i = 0; i < 4; ++i) {
            const float xk = __shfl(xv[i], k);
            const float zk = __shfl(zv[i], k);
            a0[i] += xk*w1a + zk*w2a;
            a1[i] += xk*w1b + zk*w2b;
        }
    }
    const float bb0 = bias1[lane]      + bias2[lane];
    const float bb1 = bias1[64 + lane] + bias2[64 + lane];
    float s0=0,q0=0,s1=0,q1=0;
    #pragma unroll
    for (int i = 0; i < 4; ++i) {
        const float v0 = a0[i] + bb0;
        const float v1 = a1[i] + bb1;
        t2[(size_t)(r0 + i)*128 + lane]      = v0;
        t2[(size_t)(r0 + i)*128 + 64 + lane] = v1;
        s0 += v0; q0 += v0*v0;
        s1 += v1; q1 += v1*v1;
    }
    atomicAdd(&st2[lane],        s0);
    atomicAdd(&st2[64  + lane],  s1);
    atomicAdd(&st2[128 + lane],  q0);
    atomicAdd(&st2[192 + lane],  q1);
}

// ---------------------------------------------------------------------------
// Kernel 3: out = relu(bn2(t2))
// ---------------------------------------------------------------------------
__global__ __launch_bounds__(256) void k_bn2(
    const float* __restrict__ t2, const float* __restrict__ stats,
    const float* __restrict__ g2, const float* __restrict__ b2,
    float* __restrict__ out)
{
    const int idx = blockIdx.x * 256 + threadIdx.x;
    const int c   = idx & 127;
    const float mu  = stats[c] * (1.f / NNODES);
    const float var = stats[128 + c] * (1.f / NNODES) - mu*mu;
    const float sc  = rsqrtf(var + EPS) * g2[c];
    const float sh  = b2[c] - mu*sc;
    const float v = t2[idx];
    out[idx] = fmaxf(v*sc + sh, 0.f);
}

extern "C" void kernel_launch(void* const* d_in, const int* in_sizes, int n_in,
                              void* d_out, int out_size, void* d_ws, size_t ws_size,
                              hipStream_t stream)
{
    const float* x     = (const float*)d_in[0];
    const float* p     = (const float*)d_in[1];
    const int*   sid   = (const int*)d_in[2];
    const int*   tid   = (const int*)d_in[3];
    // d_in[4] = B, d_in[5] = n (scalars, unused — constants hardcoded)
    const float* linsW = (const float*)d_in[6];
    const float* linsB = (const float*)d_in[7];
    const float* W1    = (const float*)d_in[8];
    const float* b1l   = (const float*)d_in[9];
    const float* W2    = (const float*)d_in[10];
    const float* b2l   = (const float*)d_in[11];
    const float* g1    = (const float*)d_in[12];
    const float* bb1   = (const float*)d_in[13];
    const float* g2    = (const float*)d_in[14];
    const float* bb2   = (const float*)d_in[15];

    float* ws  = (float*)d_ws;
    float* y1  = ws + Y1_OFF;
    float* t2  = ws + T2_OFF;
    float* st1 = ws + ST1_OFF;
    float* st2 = ws + ST2_OFF;

    hipMemsetAsync(st1, 0, (128 + 256) * sizeof(float), stream);

    k_node  <<<NNODES/4,          256, 0, stream>>>(x, p, sid, tid, linsW, linsB,
                                                    y1, st1);
    k_fused2<<<NNODES/16,         256, 0, stream>>>(x, tid, y1, st1, g1, bb1,
                                                    W1, b1l, W2, b2l, t2, st2);
    k_bn2   <<<(NNODES*OUTC)/256, 256, 0, stream>>>(t2, st2, g2, bb2,
                                                    (float*)d_out);
}

// Round 3
// 201.097 us; speedup vs baseline: 3.0783x; 3.0783x over previous
//
#include <hip/hip_runtime.h>

// Problem constants (fixed by setup_inputs)
#define NNODES 16384      // B*n = 8*2048
#define KEDGE  16
#define EPS    1e-5f

// Workspace layout (floats). No atomics anywhere: per-block partials + tiny
// deterministic reduction kernels (round-2 post-mortem: 2M atomics onto 2
// cache lines serialized at ~1 op/cy at the TCC = the whole 415 us).
#define Y1_OFF  0
#define T2_OFF  (NNODES*64)            // y1: 16384*64
#define P1_OFF  (T2_OFF + NNODES*128)  // t2: 16384*128
#define P2_OFF  (P1_OFF + 1024*128)    // part1: 1024 blocks x (64 sum + 64 sumsq)
#define ST1_OFF (P2_OFF + 1024*256)    // part2: 1024 blocks x (128 sum + 128 sumsq)
#define ST2_OFF (ST1_OFF + 128)

// ---------------------------------------------------------------------------
// Kernel 1: fused edge aggregation + 390x64 GEMM + BN1 block-partials.
// Block = 4 waves x 4 nodes/wave = 16 nodes. Phase 1: lane = (node i, edge j)
// -> zero redundancy on the transcendental edge math. Phase 3: 4-row GEMM per
// wave, W column loads amortized 4x.
// ---------------------------------------------------------------------------
__global__ __launch_bounds__(256) void k_node(
    const float* __restrict__ x, const float* __restrict__ p,
    const int* __restrict__ sid, const int* __restrict__ tid,
    const float* __restrict__ W, const float* __restrict__ bias,
    float* __restrict__ y1, float* __restrict__ part1)
{
    __shared__ float Ash[16][392];     // 390 used/row; 392 keeps rows 16B-aligned
    __shared__ float red[4][64][2];

    const int lane = threadIdx.x & 63;
    const int wv   = threadIdx.x >> 6;
    const int tw   = blockIdx.x * 16 + wv * 4;   // first node of this wave

    // ---- phase 1: one edge per lane (node ii = lane>>4, edge jj = lane&15)
    const int ii = lane >> 4;
    const int t1 = tw + ii;
    const int s  = sid[t1 * KEDGE + (lane & 15)];     // coalesced
    const int tn1 = tid[t1 * KEDGE];
    const float ptx = p[tn1*3+0], pty = p[tn1*3+1], ptz = p[tn1*3+2];
    const float dx = p[s*3+0] - ptx;
    const float dy = p[s*3+1] - pty;
    const float dz = p[s*3+2] - ptz;
    float pd = fmaxf(sqrtf(dx*dx + dy*dy + dz*dz), 1e-16f);

    float pr = pd;                                     // max over the 16-group
    pr = fmaxf(pr, __shfl_xor(pr, 1));
    pr = fmaxf(pr, __shfl_xor(pr, 2));
    pr = fmaxf(pr, __shfl_xor(pr, 4));
    pr = fmaxf(pr, __shfl_xor(pr, 8));
    pr *= 1.1f;

    float w = (pr - pd) * (pr - pd);
    float wsum = w;
    wsum += __shfl_xor(wsum, 1);
    wsum += __shfl_xor(wsum, 2);
    wsum += __shfl_xor(wsum, 4);
    wsum += __shfl_xor(wsum, 8);
    w /= wsum;

    const float invd = 1.f / pd;
    const float c0 = __cosf(dx * invd);   // |arg|<=1: no range reduction needed
    const float c1 = __cosf(dy * invd);
    const float c2 = __cosf(dz * invd);
    const float w0 = w * c0 * c0;
    const float w1 = w * c1 * c1;
    const float w2 = w * c2 * c2;
    const int flags = (dx > 0.f ? 1 : 0) | (dy > 0.f ? 2 : 0) | (dz > 0.f ? 4 : 0);

    // ---- phase 2: per node, gather x rows and accumulate six A vectors + betas
    #pragma unroll
    for (int i = 0; i < 4; ++i) {
        const int tn = __shfl(tn1, i * 16);
        const float xt = x[tn*64 + lane];              // lane = channel here
        float A0=0,A1=0,A2=0,A3=0,A4=0,A5=0;
        float B0=0,B1=0,B2=0,B3=0,B4=0,B5=0;
        #pragma unroll
        for (int j = 0; j < KEDGE; ++j) {
            const int src = i*16 + j;
            const int   sv = __shfl(s,  src);
            const float q0 = __shfl(w0, src);
            const float q1 = __shfl(w1, src);
            const float q2 = __shfl(w2, src);
            const int   f  = __builtin_amdgcn_readfirstlane(__shfl(flags, src));
            const float e  = x[sv*64 + lane] - xt;
            if (f & 1) { A1 += q0*e; B1 += q0; } else { A0 += q0*e; B0 += q0; }
            if (f & 2) { A3 += q1*e; B3 += q1; } else { A2 += q1*e; B2 += q1; }
            if (f & 4) { A5 += q2*e; B5 += q2; } else { A4 += q2*e; B4 += q2; }
        }
        const int r = wv*4 + i;
        Ash[r][0*64+lane] = A0; Ash[r][1*64+lane] = A1; Ash[r][2*64+lane] = A2;
        Ash[r][3*64+lane] = A3; Ash[r][4*64+lane] = A4; Ash[r][5*64+lane] = A5;
        if (lane == 0) {       // B's are lane-invariant
            Ash[r][384] = B0; Ash[r][385] = B1; Ash[r][386] = B2;
            Ash[r][387] = B3; Ash[r][388] = B4; Ash[r][389] = B5;
        }
    }
    // Ash rows are wave-private; compiler's lgkmcnt wait suffices, no barrier.

    // ---- phase 3: 4-row GEMM  y = A @ [lins_W; lins_b]
    const float* Wp = W + lane;
    const int rb = wv * 4;
    float acc[4] = {0,0,0,0};
    #pragma unroll 2
    for (int k = 0; k < 384; k += 4) {
        const float4 a0 = *(const float4*)&Ash[rb+0][k];   // uniform addr -> broadcast
        const float4 a1 = *(const float4*)&Ash[rb+1][k];
        const float4 a2 = *(const float4*)&Ash[rb+2][k];
        const float4 a3 = *(const float4*)&Ash[rb+3][k];
        const float wk0 = Wp[(k+0)*64];
        const float wk1 = Wp[(k+1)*64];
        const float wk2 = Wp[(k+2)*64];
        const float wk3 = Wp[(k+3)*64];
        acc[0] += a0.x*wk0 + a0.y*wk1 + a0.z*wk2 + a0.w*wk3;
        acc[1] += a1.x*wk0 + a1.y*wk1 + a1.z*wk2 + a1.w*wk3;
        acc[2] += a2.x*wk0 + a2.y*wk1 + a2.z*wk2 + a2.w*wk3;
        acc[3] += a3.x*wk0 + a3.y*wk1 + a3.z*wk2 + a3.w*wk3;
    }
    float bv[6];
    #pragma unroll
    for (int sx = 0; sx < 6; ++sx) bv[sx] = bias[sx*64 + lane];

    float sloc = 0.f, qloc = 0.f;
    #pragma unroll
    for (int i = 0; i < 4; ++i) {
        float a = acc[i];
        #pragma unroll
        for (int sx = 0; sx < 6; ++sx) a += Ash[rb+i][384+sx] * bv[sx];
        y1[(tw+i)*64 + lane] = a;
        sloc += a; qloc += a*a;
    }

    // ---- BN1 block partials (no atomics)
    red[wv][lane][0] = sloc;
    red[wv][lane][1] = qloc;
    __syncthreads();
    if (wv == 0) {
        const float s0 = red[0][lane][0] + red[1][lane][0] + red[2][lane][0] + red[3][lane][0];
        const float q0 = red[0][lane][1] + red[1][lane][1] + red[2][lane][1] + red[3][lane][1];
        part1[blockIdx.x*128 + lane]      = s0;
        part1[blockIdx.x*128 + 64 + lane] = q0;
    }
}

// ---------------------------------------------------------------------------
// Reduce 1024 x 128 BN1 partials -> st1[128]  (1 block)
// ---------------------------------------------------------------------------
__global__ __launch_bounds__(256) void k_red1(
    const float* __restrict__ part, float* __restrict__ st)
{
    __shared__ float red[256];
    const int c = threadIdx.x & 127;
    const int h = threadIdx.x >> 7;
    const float* pp = part + (size_t)h * 512 * 128 + c;
    float s = 0.f;
    #pragma unroll 8
    for (int b = 0; b < 512; ++b) s += pp[b*128];
    red[threadIdx.x] = s;
    __syncthreads();
    if (h == 0) st[c] = red[c] + red[128 + c];
}

// ---------------------------------------------------------------------------
// Kernel 2: t2 = x@lin1_W + relu(bn1(y1))@lin2_W + biases, BN2 block-partials.
// One wave = 4 rows; lane covers output cols {lane, lane+64}.
// ---------------------------------------------------------------------------
__global__ __launch_bounds__(256) void k_fused2(
    const float* __restrict__ x, const int* __restrict__ tid,
    const float* __restrict__ y1, const float* __restrict__ stats1,
    const float* __restrict__ g1, const float* __restrict__ b1,
    const float* __restrict__ W1, const float* __restrict__ bias1,
    const float* __restrict__ W2, const float* __restrict__ bias2,
    float* __restrict__ t2, float* __restrict__ part2)
{
    __shared__ float red[4][64][4];
    const int lane = threadIdx.x & 63;
    const int wv   = threadIdx.x >> 6;
    const int r0   = (blockIdx.x * 4 + wv) * 4;

    const float mu  = stats1[lane] * (1.f / NNODES);
    const float var = stats1[64 + lane] * (1.f / NNODES) - mu*mu;
    const float sc  = rsqrtf(var + EPS) * g1[lane];
    const float sh  = b1[lane] - mu*sc;

    float xv[4], zv[4];
    #pragma unroll
    for (int i = 0; i < 4; ++i) {
        const int tn = tid[(r0 + i) * KEDGE];
        xv[i] = x[tn*64 + lane];
        const float yv = y1[(r0 + i)*64 + lane];
        zv[i] = fmaxf(yv*sc + sh, 0.f);
    }
    float a0[4] = {0,0,0,0}, a1[4] = {0,0,0,0};
    #pragma unroll 4
    for (int k = 0; k < 64; ++k) {
        const float w1a = W1[k*128 + lane],      w1b = W1[k*128 + 64 + lane];
        const float w2a = W2[k*128 + lane],      w2b = W2[k*128 + 64 + lane];
        #pragma unroll
        for (int i = 0; i < 4; ++i) {
            const float xk = __shfl(xv[i], k);
            const float zk = __shfl(zv[i], k);
            a0[i] += xk*w1a + zk*w2a;
            a1[i] += xk*w1b + zk*w2b;
        }
    }
    const float bb0 = bias1[lane]      + bias2[lane];
    const float bb1 = bias1[64 + lane] + bias2[64 + lane];
    float s0=0,q0=0,s1=0,q1=0;
    #pragma unroll
    for (int i = 0; i < 4; ++i) {
        const float v0 = a0[i] + bb0;
        const float v1 = a1[i] + bb1;
        t2[(size_t)(r0 + i)*128 + lane]      = v0;
        t2[(size_t)(r0 + i)*128 + 64 + lane] = v1;
        s0 += v0; q0 += v0*v0;
        s1 += v1; q1 += v1*v1;
    }
    red[wv][lane][0] = s0; red[wv][lane][1] = s1;
    red[wv][lane][2] = q0; red[wv][lane][3] = q1;
    __syncthreads();
    if (wv == 0) {
        float t0=0, t1v=0, t2v=0, t3=0;
        #pragma unroll
        for (int v = 0; v < 4; ++v) {
            t0  += red[v][lane][0]; t1v += red[v][lane][1];
            t2v += red[v][lane][2]; t3  += red[v][lane][3];
        }
        float* pr = part2 + blockIdx.x * 256;
        pr[lane]       = t0;    // sum, cols 0..63
        pr[64 + lane]  = t1v;   // sum, cols 64..127
        pr[128 + lane] = t2v;   // sumsq, cols 0..63
        pr[192 + lane] = t3;    // sumsq, cols 64..127
    }
}

// ---------------------------------------------------------------------------
// Reduce 1024 x 256 BN2 partials -> st2[256]  (2 blocks)
// ---------------------------------------------------------------------------
__global__ __launch_bounds__(256) void k_red2(
    const float* __restrict__ part, float* __restrict__ st)
{
    __shared__ float red[256];
    const int c = blockIdx.x * 128 + (threadIdx.x & 127);
    const int h = threadIdx.x >> 7;
    const float* pp = part + (size_t)h * 512 * 256 + c;
    float s = 0.f;
    #pragma unroll 8
    for (int b = 0; b < 512; ++b) s += pp[b*256];
    red[threadIdx.x] = s;
    __syncthreads();
    if (h == 0) st[c] = red[threadIdx.x] + red[threadIdx.x + 128];
}

// ---------------------------------------------------------------------------
// Kernel 3: out = relu(bn2(t2))
// ---------------------------------------------------------------------------
__global__ __launch_bounds__(256) void k_bn2(
    const float* __restrict__ t2, const float* __restrict__ stats,
    const float* __restrict__ g2, const float* __restrict__ b2,
    float* __restrict__ out)
{
    const int idx = blockIdx.x * 256 + threadIdx.x;
    const int c   = idx & 127;
    const float mu  = stats[c] * (1.f / NNODES);
    const float var = stats[128 + c] * (1.f / NNODES) - mu*mu;
    const float sc  = rsqrtf(var + EPS) * g2[c];
    const float sh  = b2[c] - mu*sc;
    const float v = t2[idx];
    out[idx] = fmaxf(v*sc + sh, 0.f);
}

extern "C" void kernel_launch(void* const* d_in, const int* in_sizes, int n_in,
                              void* d_out, int out_size, void* d_ws, size_t ws_size,
                              hipStream_t stream)
{
    const float* x     = (const float*)d_in[0];
    const float* p     = (const float*)d_in[1];
    const int*   sid   = (const int*)d_in[2];
    const int*   tid   = (const int*)d_in[3];
    // d_in[4] = B, d_in[5] = n (scalars, unused — constants hardcoded)
    const float* linsW = (const float*)d_in[6];
    const float* linsB = (const float*)d_in[7];
    const float* W1    = (const float*)d_in[8];
    const float* b1l   = (const float*)d_in[9];
    const float* W2    = (const float*)d_in[10];
    const float* b2l   = (const float*)d_in[11];
    const float* g1    = (const float*)d_in[12];
    const float* bb1   = (const float*)d_in[13];
    const float* g2    = (const float*)d_in[14];
    const float* bb2   = (const float*)d_in[15];

    float* ws    = (float*)d_ws;
    float* y1    = ws + Y1_OFF;
    float* t2    = ws + T2_OFF;
    float* part1 = ws + P1_OFF;
    float* part2 = ws + P2_OFF;
    float* st1   = ws + ST1_OFF;
    float* st2   = ws + ST2_OFF;

    k_node  <<<NNODES/16,         256, 0, stream>>>(x, p, sid, tid, linsW, linsB,
                                                    y1, part1);
    k_red1  <<<1,                 256, 0, stream>>>(part1, st1);
    k_fused2<<<NNODES/16,         256, 0, stream>>>(x, tid, y1, st1, g1, bb1,
                                                    W1, b1l, W2, b2l, t2, part2);
    k_red2  <<<2,                 256, 0, stream>>>(part2, st2);
    k_bn2   <<<(NNODES*128)/256,  256, 0, stream>>>(t2, st2, g2, bb2,
                                                    (float*)d_out);
}

// Round 4
// 172.311 us; speedup vs baseline: 3.5926x; 1.1671x over previous
//
#include <hip/hip_runtime.h>

// Problem constants (fixed by setup_inputs)
#define NNODES 16384      // B*n = 8*2048
#define KEDGE  16
#define EPS    1e-5f

// Workspace layout (floats).
// Round-2 lesson: 2M atomics on 2 lines = 415 us serialization.
// Round-3 lesson: 1-block reductions = ~40 us of single-CU latency.
// Round 4: per-WAVE partial rows (no barrier) + 64-block reduction with one
// atomicAdd per channel per block (64-way contention == ~us).
#define Y1_OFF  0
#define T2_OFF  (NNODES*64)             // y1: 16384*64
#define P1_OFF  (T2_OFF + NNODES*128)   // t2: 16384*128
#define P2_OFF  (P1_OFF + 4096*128)     // part1: 4096 waves x (64 sum + 64 sumsq)
#define ST1_OFF (P2_OFF + 4096*256)     // part2: 4096 waves x (128 sum + 128 sumsq)
#define ST2_OFF (ST1_OFF + 128)

// ---------------------------------------------------------------------------
// Kernel 1: fused edge aggregation + 390x64 GEMM + per-wave BN1 partials.
// Block = 4 waves x 4 nodes/wave = 16 nodes. Phase 1: lane = (node, edge) ->
// zero redundancy on transcendentals. Phase 3: 4-row GEMM per wave. No
// __syncthreads anywhere: Ash rows are wave-private, partials are per-wave.
// ---------------------------------------------------------------------------
__global__ __launch_bounds__(256) void k_node(
    const float* __restrict__ x, const float* __restrict__ p,
    const int* __restrict__ sid, const int* __restrict__ tid,
    const float* __restrict__ W, const float* __restrict__ bias,
    float* __restrict__ y1, float* __restrict__ part1)
{
    __shared__ float Ash[16][392];     // 390 used/row; 392 keeps rows 16B-aligned

    const int lane = threadIdx.x & 63;
    const int wv   = threadIdx.x >> 6;
    const int tw   = blockIdx.x * 16 + wv * 4;   // first node of this wave

    // ---- phase 1: one edge per lane (node ii = lane>>4, edge jj = lane&15)
    const int ii = lane >> 4;
    const int t1 = tw + ii;
    const int s  = sid[t1 * KEDGE + (lane & 15)];     // coalesced
    const int tn1 = tid[t1 * KEDGE];
    const float ptx = p[tn1*3+0], pty = p[tn1*3+1], ptz = p[tn1*3+2];
    const float dx = p[s*3+0] - ptx;
    const float dy = p[s*3+1] - pty;
    const float dz = p[s*3+2] - ptz;
    float pd = fmaxf(sqrtf(dx*dx + dy*dy + dz*dz), 1e-16f);

    float pr = pd;                                     // max over the 16-group
    pr = fmaxf(pr, __shfl_xor(pr, 1));
    pr = fmaxf(pr, __shfl_xor(pr, 2));
    pr = fmaxf(pr, __shfl_xor(pr, 4));
    pr = fmaxf(pr, __shfl_xor(pr, 8));
    pr *= 1.1f;

    float w = (pr - pd) * (pr - pd);
    float wsum = w;
    wsum += __shfl_xor(wsum, 1);
    wsum += __shfl_xor(wsum, 2);
    wsum += __shfl_xor(wsum, 4);
    wsum += __shfl_xor(wsum, 8);
    w /= wsum;

    const float invd = 1.f / pd;
    const float c0 = __cosf(dx * invd);   // |arg|<=1: no range reduction needed
    const float c1 = __cosf(dy * invd);
    const float c2 = __cosf(dz * invd);
    const float w0 = w * c0 * c0;
    const float w1 = w * c1 * c1;
    const float w2 = w * c2 * c2;
    const int flags = (dx > 0.f ? 1 : 0) | (dy > 0.f ? 2 : 0) | (dz > 0.f ? 4 : 0);

    // ---- phase 2: per node, gather x rows and accumulate six A vectors + betas
    #pragma unroll
    for (int i = 0; i < 4; ++i) {
        const int tn = __shfl(tn1, i * 16);
        const float xt = x[tn*64 + lane];              // lane = channel here
        float A0=0,A1=0,A2=0,A3=0,A4=0,A5=0;
        float B0=0,B1=0,B2=0,B3=0,B4=0,B5=0;
        #pragma unroll
        for (int j = 0; j < KEDGE; ++j) {
            const int src = i*16 + j;
            const int   sv = __shfl(s,  src);
            const float q0 = __shfl(w0, src);
            const float q1 = __shfl(w1, src);
            const float q2 = __shfl(w2, src);
            const int   f  = __builtin_amdgcn_readfirstlane(__shfl(flags, src));
            const float e  = x[sv*64 + lane] - xt;
            if (f & 1) { A1 += q0*e; B1 += q0; } else { A0 += q0*e; B0 += q0; }
            if (f & 2) { A3 += q1*e; B3 += q1; } else { A2 += q1*e; B2 += q1; }
            if (f & 4) { A5 += q2*e; B5 += q2; } else { A4 += q2*e; B4 += q2; }
        }
        const int r = wv*4 + i;
        Ash[r][0*64+lane] = A0; Ash[r][1*64+lane] = A1; Ash[r][2*64+lane] = A2;
        Ash[r][3*64+lane] = A3; Ash[r][4*64+lane] = A4; Ash[r][5*64+lane] = A5;
        if (lane == 0) {       // B's are lane-invariant
            Ash[r][384] = B0; Ash[r][385] = B1; Ash[r][386] = B2;
            Ash[r][387] = B3; Ash[r][388] = B4; Ash[r][389] = B5;
        }
    }
    // Ash rows are wave-private; compiler's lgkmcnt wait suffices, no barrier.

    // ---- phase 3: 4-row GEMM  y = A @ [lins_W; lins_b]
    const float* Wp = W + lane;
    const int rb = wv * 4;
    float acc[4] = {0,0,0,0};
    #pragma unroll 2
    for (int k = 0; k < 384; k += 4) {
        const float4 a0 = *(const float4*)&Ash[rb+0][k];   // uniform addr -> broadcast
        const float4 a1 = *(const float4*)&Ash[rb+1][k];
        const float4 a2 = *(const float4*)&Ash[rb+2][k];
        const float4 a3 = *(const float4*)&Ash[rb+3][k];
        const float wk0 = Wp[(k+0)*64];
        const float wk1 = Wp[(k+1)*64];
        const float wk2 = Wp[(k+2)*64];
        const float wk3 = Wp[(k+3)*64];
        acc[0] += a0.x*wk0 + a0.y*wk1 + a0.z*wk2 + a0.w*wk3;
        acc[1] += a1.x*wk0 + a1.y*wk1 + a1.z*wk2 + a1.w*wk3;
        acc[2] += a2.x*wk0 + a2.y*wk1 + a2.z*wk2 + a2.w*wk3;
        acc[3] += a3.x*wk0 + a3.y*wk1 + a3.z*wk2 + a3.w*wk3;
    }
    float bv[6];
    #pragma unroll
    for (int sx = 0; sx < 6; ++sx) bv[sx] = bias[sx*64 + lane];

    float sloc = 0.f, qloc = 0.f;
    #pragma unroll
    for (int i = 0; i < 4; ++i) {
        float a = acc[i];
        #pragma unroll
        for (int sx = 0; sx < 6; ++sx) a += Ash[rb+i][384+sx] * bv[sx];
        y1[(tw+i)*64 + lane] = a;
        sloc += a; qloc += a*a;
    }

    // ---- per-wave BN1 partial row (no barrier, no contention)
    const int row = blockIdx.x * 4 + wv;
    part1[row*128 + lane]      = sloc;
    part1[row*128 + 64 + lane] = qloc;
}

// ---------------------------------------------------------------------------
// Reduce 4096 x 128 BN1 partials -> st1[128].
// 64 blocks x 64 rows each; one atomicAdd per channel per block (64-way).
// ---------------------------------------------------------------------------
__global__ __launch_bounds__(256) void k_red1(
    const float* __restrict__ part, float* __restrict__ st)
{
    __shared__ float red[256];
    const int c = threadIdx.x & 127;
    const int h = threadIdx.x >> 7;            // 0/1: rows [0,32) / [32,64)
    const float* pp = part + ((size_t)blockIdx.x * 64 + h * 32) * 128 + c;
    float s = 0.f;
    #pragma unroll 8
    for (int b = 0; b < 32; ++b) s += pp[b*128];
    red[threadIdx.x] = s;
    __syncthreads();
    if (h == 0) atomicAdd(&st[c], red[c] + red[128 + c]);
}

// ---------------------------------------------------------------------------
// Kernel 2: t2 = x@lin1_W + relu(bn1(y1))@lin2_W + biases, per-wave BN2
// partials. One wave = 4 rows; lane covers output cols {lane, lane+64}.
// ---------------------------------------------------------------------------
__global__ __launch_bounds__(256) void k_fused2(
    const float* __restrict__ x, const int* __restrict__ tid,
    const float* __restrict__ y1, const float* __restrict__ stats1,
    const float* __restrict__ g1, const float* __restrict__ b1,
    const float* __restrict__ W1, const float* __restrict__ bias1,
    const float* __restrict__ W2, const float* __restrict__ bias2,
    float* __restrict__ t2, float* __restrict__ part2)
{
    const int lane = threadIdx.x & 63;
    const int wv   = threadIdx.x >> 6;
    const int r0   = (blockIdx.x * 4 + wv) * 4;

    const float mu  = stats1[lane] * (1.f / NNODES);
    const float var = stats1[64 + lane] * (1.f / NNODES) - mu*mu;
    const float sc  = rsqrtf(var + EPS) * g1[lane];
    const float sh  = b1[lane] - mu*sc;

    float xv[4], zv[4];
    #pragma unroll
    for (int i = 0; i < 4; ++i) {
        const int tn = tid[(r0 + i) * KEDGE];
        xv[i] = x[tn*64 + lane];
        const float yv = y1[(r0 + i)*64 + lane];
        zv[i] = fmaxf(yv*sc + sh, 0.f);
    }
    float a0[4] = {0,0,0,0}, a1[4] = {0,0,0,0};
    #pragma unroll 4
    for (int k = 0; k < 64; ++k) {
        const float w1a = W1[k*128 + lane],      w1b = W1[k*128 + 64 + lane];
        const float w2a = W2[k*128 + lane],      w2b = W2[k*128 + 64 + lane];
        #pragma unroll
        for (int i = 0; i < 4; ++i) {
            const float xk = __shfl(xv[i], k);
            const float zk = __shfl(zv[i], k);
            a0[i] += xk*w1a + zk*w2a;
            a1[i] += xk*w1b + zk*w2b;
        }
    }
    const float bb0 = bias1[lane]      + bias2[lane];
    const float bb1 = bias1[64 + lane] + bias2[64 + lane];
    float s0=0,q0=0,s1=0,q1=0;
    #pragma unroll
    for (int i = 0; i < 4; ++i) {
        const float v0 = a0[i] + bb0;
        const float v1 = a1[i] + bb1;
        t2[(size_t)(r0 + i)*128 + lane]      = v0;
        t2[(size_t)(r0 + i)*128 + 64 + lane] = v1;
        s0 += v0; q0 += v0*v0;
        s1 += v1; q1 += v1*v1;
    }
    // per-wave BN2 partial row (sum[0..127], sumsq[128..255])
    float* pr = part2 + ((size_t)blockIdx.x * 4 + wv) * 256;
    pr[lane]       = s0;
    pr[64 + lane]  = s1;
    pr[128 + lane] = q0;
    pr[192 + lane] = q1;
}

// ---------------------------------------------------------------------------
// Reduce 4096 x 256 BN2 partials -> st2[256].
// 64 blocks x 64 rows; each thread owns one of 256 columns; one atomic each.
// ---------------------------------------------------------------------------
__global__ __launch_bounds__(256) void k_red2(
    const float* __restrict__ part, float* __restrict__ st)
{
    const int c = threadIdx.x;
    const float* pp = part + (size_t)blockIdx.x * 64 * 256 + c;
    float s = 0.f;
    #pragma unroll 8
    for (int b = 0; b < 64; ++b) s += pp[b*256];
    atomicAdd(&st[c], s);
}

// ---------------------------------------------------------------------------
// Kernel 3: out = relu(bn2(t2))
// ---------------------------------------------------------------------------
__global__ __launch_bounds__(256) void k_bn2(
    const float* __restrict__ t2, const float* __restrict__ stats,
    const float* __restrict__ g2, const float* __restrict__ b2,
    float* __restrict__ out)
{
    const int idx = blockIdx.x * 256 + threadIdx.x;
    const int c   = idx & 127;
    const float mu  = stats[c] * (1.f / NNODES);
    const float var = stats[128 + c] * (1.f / NNODES) - mu*mu;
    const float sc  = rsqrtf(var + EPS) * g2[c];
    const float sh  = b2[c] - mu*sc;
    const float v = t2[idx];
    out[idx] = fmaxf(v*sc + sh, 0.f);
}

extern "C" void kernel_launch(void* const* d_in, const int* in_sizes, int n_in,
                              void* d_out, int out_size, void* d_ws, size_t ws_size,
                              hipStream_t stream)
{
    const float* x     = (const float*)d_in[0];
    const float* p     = (const float*)d_in[1];
    const int*   sid   = (const int*)d_in[2];
    const int*   tid   = (const int*)d_in[3];
    // d_in[4] = B, d_in[5] = n (scalars, unused — constants hardcoded)
    const float* linsW = (const float*)d_in[6];
    const float* linsB = (const float*)d_in[7];
    const float* W1    = (const float*)d_in[8];
    const float* b1l   = (const float*)d_in[9];
    const float* W2    = (const float*)d_in[10];
    const float* b2l   = (const float*)d_in[11];
    const float* g1    = (const float*)d_in[12];
    const float* bb1   = (const float*)d_in[13];
    const float* g2    = (const float*)d_in[14];
    const float* bb2   = (const float*)d_in[15];

    float* ws    = (float*)d_ws;
    float* y1    = ws + Y1_OFF;
    float* t2    = ws + T2_OFF;
    float* part1 = ws + P1_OFF;
    float* part2 = ws + P2_OFF;
    float* st1   = ws + ST1_OFF;
    float* st2   = ws + ST2_OFF;

    hipMemsetAsync(st1, 0, (128 + 256) * sizeof(float), stream);

    k_node  <<<NNODES/16,         256, 0, stream>>>(x, p, sid, tid, linsW, linsB,
                                                    y1, part1);
    k_red1  <<<64,                256, 0, stream>>>(part1, st1);
    k_fused2<<<NNODES/16,         256, 0, stream>>>(x, tid, y1, st1, g1, bb1,
                                                    W1, b1l, W2, b2l, t2, part2);
    k_red2  <<<64,                256, 0, stream>>>(part2, st2);
    k_bn2   <<<(NNODES*128)/256,  256, 0, stream>>>(t2, st2, g2, bb2,
                                                    (float*)d_out);
}